// Round 9
// baseline (370.056 us; speedup 1.0000x reference)
//
#include <hip/hip_runtime.h>

typedef _Float16 h16x8 __attribute__((ext_vector_type(8)));
typedef _Float16 h16x4 __attribute__((ext_vector_type(4)));
typedef float    f32x4 __attribute__((ext_vector_type(4)));

#define NDIM   12288
#define KDIM   4096
#define MDIM   256
#define N_TILE 48
#define NT     32                      // K tiles of 128 (= GROUP_SIZE)
#define TILE_BYTES 6144                // 48 rows x 128 k, int8
#define XF_BYTES    ((size_t)MDIM * KDIM * 2)          // 2 MB
#define TILES_BYTES ((size_t)256 * 32 * TILE_BYTES)    // 48 MB

// Pre-pass 1: x f32 -> f16 (exact: x was originally fp16).
__global__ __launch_bounds__(256) void cvt_x_kernel(const float* __restrict__ x,
                                                    _Float16* __restrict__ xf) {
    int i = blockIdx.x * 256 + threadIdx.x;
    f32x4 v = *(const f32x4*)(x + (size_t)i * 4);
    h16x4 h;
    h[0] = (_Float16)v[0]; h[1] = (_Float16)v[1];
    h[2] = (_Float16)v[2]; h[3] = (_Float16)v[3];
    *(h16x4*)(xf + (size_t)i * 4) = h;
}

// Pre-pass 2: repack W int32 -> int8 tiles [blk 256][t 32][row 48][k 128].
// Reads are perfectly LINEAR (thread g reads 64B at wq + g*64B); this converts
// qlin's W stream from 512B@16KB-stride (measured ~1.7 TB/s) to contiguous.
__global__ __launch_bounds__(1024) void repack_kernel(const int* __restrict__ wq,
                                                      unsigned char* __restrict__ tiles) {
    const int G = blockIdx.x * 1024 + threadIdx.x;   // 0 .. 3,145,727
    const int n    = G >> 8;                         // output row 0..12287
    const int koff = (G & 255) << 4;                 // k offset, 16 values/thread
    const int4* src = (const int4*)(wq + (size_t)n * KDIM + koff);
    int4 v0 = src[0], v1 = src[1], v2 = src[2], v3 = src[3];
    uint4 P;
    P.x = (v0.x & 255) | ((v0.y & 255) << 8) | ((v0.z & 255) << 16) | ((v0.w & 255) << 24);
    P.y = (v1.x & 255) | ((v1.y & 255) << 8) | ((v1.z & 255) << 16) | ((v1.w & 255) << 24);
    P.z = (v2.x & 255) | ((v2.y & 255) << 8) | ((v2.z & 255) << 16) | ((v2.w & 255) << 24);
    P.w = (v3.x & 255) | ((v3.y & 255) << 8) | ((v3.z & 255) << 16) | ((v3.w & 255) << 24);
    const int t = koff >> 7, kb = koff & 127;
    const int blk = n / 48, row = n - blk * 48;
    *(uint4*)(tiles + (size_t)(blk * 32 + t) * TILE_BYTES + row * 128 + kb) = P;
}

// Main GEMM: 256 blocks x 1024 threads (16 waves). Block tile 256m x 48n, full K.
// W arrives as contiguous int8 tiles (L3-hot); dequant at staging (same math as
// the passing rounds); counted barriers keep tile prefetch loads in flight.
__global__ __launch_bounds__(1024, 4) void qlin_tiles(
    const _Float16*      __restrict__ xf16,   // [256][4096] f16 (ws)
    const float*         __restrict__ scales, // [12288][32] fp32
    const float*         __restrict__ bias,   // [12288]     fp32
    const unsigned char* __restrict__ tiles,  // [256][32][48][128] int8 (ws)
    float*               __restrict__ out)    // [256][12288] fp32
{
    __shared__ char  wl[2][N_TILE * 256];   // dequant f16 W, XOR-swizzled
    __shared__ float sc[N_TILE * 32];

    const int tid  = threadIdx.x;
    const int lane = tid & 63;
    const int wave = tid >> 6;              // 0..15
    const int n0   = blockIdx.x * N_TILE;

    for (int j = tid; j < N_TILE * 32; j += 1024)
        sc[j] = scales[(size_t)(n0 + (j >> 5)) * 32 + (j & 31)];

    // Staging map (threads 0..767): thread = (row, 8 k-values), reads 8B
    // contiguous; 768 threads cover the 6KB tile linearly.
    const int srow = tid >> 4;              // 0..63 (used < 48)
    const int skb  = (tid & 15) * 8;        // int8 k offset in row
    const bool do_stage = tid < N_TILE * 16;
    const unsigned char* tb = tiles + (size_t)blockIdx.x * 32 * TILE_BYTES
                                    + srow * 128 + skb;
    const int wdst = srow * 256 + ((skb * 2) ^ ((srow & 7) << 4));  // swizzled f16 bytes

    auto ldq = [&](int t) -> int2 {
        return do_stage ? *(const int2*)(tb + (size_t)t * TILE_BYTES) : int2{0, 0};
    };
    auto stage = [&](int buf, int t, int2 q) {
        if (do_stage) {
            float s = sc[srow * 32 + t];
            int a = q.x, b = q.y;
            h16x8 h;
            h[0] = (_Float16)((float)((a << 24) >> 24) * s);
            h[1] = (_Float16)((float)((a << 16) >> 24) * s);
            h[2] = (_Float16)((float)((a <<  8) >> 24) * s);
            h[3] = (_Float16)((float)( a        >> 24) * s);
            h[4] = (_Float16)((float)((b << 24) >> 24) * s);
            h[5] = (_Float16)((float)((b << 16) >> 24) * s);
            h[6] = (_Float16)((float)((b <<  8) >> 24) * s);
            h[7] = (_Float16)((float)( b        >> 24) * s);
            *(h16x8*)(&wl[buf][wdst]) = h;
        }
    };

    // MFMA fragment addressing (16x16x32 f16); A/B share the k map -> HW order cancels
    const int arow = lane & 15;
    const int g16  = lane >> 4;
    const int xorv = (arow & 7) << 4;
    const size_t aidx0 = (size_t)(wave * 16 + arow) * KDIM + g16 * 8;

    f32x4 acc0 = {0.f, 0.f, 0.f, 0.f}, acc1 = acc0, acc2 = acc0;

    __syncthreads();                        // sc visible

    int2 q0 = ldq(0);
    stage(0, 0, q0);
    int2 qa = ldq(1), qb = ldq(2);          // 2-deep register prefetch
    asm volatile("s_waitcnt lgkmcnt(0)" ::: "memory");
    __builtin_amdgcn_s_barrier();           // buf0 ready; qa/qb stay in flight

    for (int t = 0; t < NT; ++t) {
        const char* bufr = &wl[t & 1][0];

        const size_t ab = aidx0 + (size_t)t * 128;
        h16x8 a0 = *(const h16x8*)(xf16 + ab);
        h16x8 a1 = *(const h16x8*)(xf16 + ab + 32);
        h16x8 a2 = *(const h16x8*)(xf16 + ab + 64);
        h16x8 a3 = *(const h16x8*)(xf16 + ab + 96);
        int2 qn = ldq(t + 3 < NT ? t + 3 : NT - 1);

        #pragma unroll
        for (int kk = 0; kk < 4; ++kk) {
            const int bo = (kk * 64 + g16 * 16) ^ xorv;
            h16x8 b0 = *(const h16x8*)(bufr + (     arow) * 256 + bo);
            h16x8 b1 = *(const h16x8*)(bufr + (16 + arow) * 256 + bo);
            h16x8 b2 = *(const h16x8*)(bufr + (32 + arow) * 256 + bo);
            h16x8 a  = (kk == 0) ? a0 : (kk == 1) ? a1 : (kk == 2) ? a2 : a3;
            acc0 = __builtin_amdgcn_mfma_f32_16x16x32_f16(a, b0, acc0, 0, 0, 0);
            acc1 = __builtin_amdgcn_mfma_f32_16x16x32_f16(a, b1, acc1, 0, 0, 0);
            acc2 = __builtin_amdgcn_mfma_f32_16x16x32_f16(a, b2, acc2, 0, 0, 0);
        }

        if (t + 1 < NT) {
            stage((t + 1) & 1, t + 1, qa);
            asm volatile("s_waitcnt lgkmcnt(0)" ::: "memory");
            __builtin_amdgcn_s_barrier();
        }
        qa = qb; qb = qn;
    }

    // Epilogue: D row = 4*(lane>>4)+r, col = lane&15 (m89-verified)
    float bv0 = bias[n0 +      arow];
    float bv1 = bias[n0 + 16 + arow];
    float bv2 = bias[n0 + 32 + arow];
    #pragma unroll
    for (int r = 0; r < 4; ++r) {
        int m = wave * 16 + g16 * 4 + r;
        float* op = out + (size_t)m * NDIM + n0 + arow;
        op[0]  = acc0[r] + bv0;
        op[16] = acc1[r] + bv1;
        op[32] = acc2[r] + bv2;
    }
}

// Fallback (ws too small): round-8 direct-W kernel, f32 x path.
__global__ __launch_bounds__(1024, 4) void qlin_direct(
    const float* __restrict__ xf32, const float* __restrict__ scales,
    const float* __restrict__ bias, const int* __restrict__ wq,
    float* __restrict__ out)
{
    __shared__ char  wl[2][N_TILE * 256];
    __shared__ float sc[N_TILE * 32];
    const int tid = threadIdx.x, lane = tid & 63, wave = tid >> 6;
    const int n0 = blockIdx.x * N_TILE;
    for (int j = tid; j < N_TILE * 32; j += 1024)
        sc[j] = scales[(size_t)(n0 + (j >> 5)) * 32 + (j & 31)];
    typedef _Float16 h16x2 __attribute__((ext_vector_type(2)));
    const int2* wb0 = (const int2*)wq + (size_t)(n0 + wave     ) * 2048 + lane;
    const int2* wb1 = (const int2*)wq + (size_t)(n0 + wave + 16) * 2048 + lane;
    const int2* wb2 = (const int2*)wq + (size_t)(n0 + wave + 32) * 2048 + lane;
    const int xors = (wave & 7) << 4;
    const int wo0 = (wave     ) * 256 + ((lane * 4) ^ xors);
    const int wo1 = (wave + 16) * 256 + ((lane * 4) ^ xors);
    const int wo2 = (wave + 32) * 256 + ((lane * 4) ^ xors);
    auto cw = [&](char* buf, int g, int2 a, int2 b, int2 c) {
        float s0 = sc[(wave)*32+g], s1 = sc[(wave+16)*32+g], s2 = sc[(wave+32)*32+g];
        h16x2 h;
        h[0]=(_Float16)((float)a.x*s0); h[1]=(_Float16)((float)a.y*s0); *(h16x2*)(buf+wo0)=h;
        h[0]=(_Float16)((float)b.x*s1); h[1]=(_Float16)((float)b.y*s1); *(h16x2*)(buf+wo1)=h;
        h[0]=(_Float16)((float)c.x*s2); h[1]=(_Float16)((float)c.y*s2); *(h16x2*)(buf+wo2)=h;
    };
    const int arow = lane & 15, g16 = lane >> 4;
    const int xorv = (arow & 7) << 4;
    const size_t aidx0 = (size_t)(wave * 16 + arow) * KDIM + g16 * 8;
    auto load_a = [&](size_t idx) -> h16x8 {
        f32x4 u0 = *(const f32x4*)(xf32 + idx);
        f32x4 u1 = *(const f32x4*)(xf32 + idx + 4);
        h16x8 a;
        a[0]=(_Float16)u0[0]; a[1]=(_Float16)u0[1]; a[2]=(_Float16)u0[2]; a[3]=(_Float16)u0[3];
        a[4]=(_Float16)u1[0]; a[5]=(_Float16)u1[1]; a[6]=(_Float16)u1[2]; a[7]=(_Float16)u1[3];
        return a;
    };
    f32x4 acc0 = {0.f,0.f,0.f,0.f}, acc1 = acc0, acc2 = acc0;
    __syncthreads();
    int2 q00=wb0[0], q01=wb1[0], q02=wb2[0];
    int2 qa0=wb0[64], qa1=wb1[64], qa2=wb2[64];
    int2 qb0=wb0[128], qb1=wb1[128], qb2=wb2[128];
    cw(&wl[0][0], 0, q00, q01, q02);
    asm volatile("s_waitcnt lgkmcnt(0)" ::: "memory");
    __builtin_amdgcn_s_barrier();
    for (int t = 0; t < NT; ++t) {
        char* bufr = &wl[t & 1][0];
        char* bufw = &wl[(t + 1) & 1][0];
        const size_t ab = aidx0 + (size_t)t * 128;
        h16x8 a0 = load_a(ab), a1 = load_a(ab + 32), a2 = load_a(ab + 64), a3 = load_a(ab + 96);
        const int tn = (t + 3 < NT) ? (t + 3) * 64 : (NT - 1) * 64;
        int2 qn0 = wb0[tn], qn1 = wb1[tn], qn2 = wb2[tn];
        #pragma unroll
        for (int kk = 0; kk < 4; ++kk) {
            const int bo = (kk * 64 + g16 * 16) ^ xorv;
            h16x8 b0 = *(const h16x8*)(bufr + (     arow) * 256 + bo);
            h16x8 b1 = *(const h16x8*)(bufr + (16 + arow) * 256 + bo);
            h16x8 b2 = *(const h16x8*)(bufr + (32 + arow) * 256 + bo);
            h16x8 a  = (kk == 0) ? a0 : (kk == 1) ? a1 : (kk == 2) ? a2 : a3;
            acc0 = __builtin_amdgcn_mfma_f32_16x16x32_f16(a, b0, acc0, 0, 0, 0);
            acc1 = __builtin_amdgcn_mfma_f32_16x16x32_f16(a, b1, acc1, 0, 0, 0);
            acc2 = __builtin_amdgcn_mfma_f32_16x16x32_f16(a, b2, acc2, 0, 0, 0);
        }
        if (t + 1 < NT) {
            cw(bufw, t + 1, qa0, qa1, qa2);
            asm volatile("s_waitcnt lgkmcnt(0)" ::: "memory");
            __builtin_amdgcn_s_barrier();
        }
        qa0=qb0; qa1=qb1; qa2=qb2; qb0=qn0; qb1=qn1; qb2=qn2;
    }
    float bv0 = bias[n0 + arow], bv1 = bias[n0 + 16 + arow], bv2 = bias[n0 + 32 + arow];
    #pragma unroll
    for (int r = 0; r < 4; ++r) {
        int m = wave * 16 + g16 * 4 + r;
        float* op = out + (size_t)m * NDIM + n0 + arow;
        op[0] = acc0[r] + bv0; op[16] = acc1[r] + bv1; op[32] = acc2[r] + bv2;
    }
}

extern "C" void kernel_launch(void* const* d_in, const int* in_sizes, int n_in,
                              void* d_out, int out_size, void* d_ws, size_t ws_size,
                              hipStream_t stream) {
    const float* x      = (const float*)d_in[0];
    const float* scales = (const float*)d_in[1];
    const float* bias   = (const float*)d_in[2];
    const int*   wq     = (const int*)d_in[3];
    float*       out    = (float*)d_out;

    if (ws_size >= XF_BYTES + TILES_BYTES) {
        _Float16*      xf    = (_Float16*)d_ws;
        unsigned char* tiles = (unsigned char*)d_ws + XF_BYTES;
        cvt_x_kernel<<<dim3(MDIM * KDIM / 1024), dim3(256), 0, stream>>>(x, xf);
        repack_kernel<<<dim3(NDIM * KDIM / 16 / 1024), dim3(1024), 0, stream>>>(wq, tiles);
        qlin_tiles<<<dim3(NDIM / N_TILE), dim3(1024), 0, stream>>>(xf, scales, bias, tiles, out);
    } else {
        qlin_direct<<<dim3(NDIM / N_TILE), dim3(1024), 0, stream>>>(x, scales, bias, wq, out);
    }
}